// Round 4
// baseline (514.966 us; speedup 1.0000x reference)
//
#include <hip/hip_runtime.h>
#include <math.h>

#define B_  8
#define L_  256
#define D_  512
#define E_  64
#define DE_ 576
#define R_  2048   // B*L rows per graph
#define RG_ 4096   // rows, both graphs stacked

// ---------------------------------------------------------------------------
// Precompute: per (g,b,i): innum/outnum = count(adj>0)+eps, and
// esum[g,b,i,:] = sum_j adj[b,i,j] * emb[edge[b,i,j],:]
// Grid: 4096 blocks (2 graphs * 2048 rows), 256 threads.
// Thread layout: e4 = t&15 (float4 lane of E=64), jc = t>>4 (16 j-chunks).
// ---------------------------------------------------------------------------
__global__ __launch_bounds__(256) void k_precompute(
    const float* __restrict__ adj1, const float* __restrict__ adj2,
    const int* __restrict__ edge1, const int* __restrict__ edge2,
    const float* __restrict__ emb,
    float* __restrict__ esum, float* __restrict__ num)
{
  int g = blockIdx.x >> 11;
  int r = blockIdx.x & 2047;               // b*L + i
  const float* adj  = (g ? adj2 : adj1) + (size_t)r * L_;
  const int*   edge = (g ? edge2 : edge1) + (size_t)r * L_;
  const float4* emb4 = (const float4*)emb;

  int t = threadIdx.x;
  int e4 = t & 15, jc = t >> 4;
  float4 acc = {0.f, 0.f, 0.f, 0.f};
  float cnt = 0.f;
  #pragma unroll
  for (int k = 0; k < 16; ++k) {
    int j = jc * 16 + k;
    float a = adj[j];
    if (a != 0.0f) {
      int id = edge[j];
      float4 e = emb4[(size_t)id * 16 + e4];
      acc.x += a * e.x; acc.y += a * e.y; acc.z += a * e.z; acc.w += a * e.w;
      if (e4 == 0 && a > 0.0f) cnt += 1.0f;
    }
  }

  __shared__ float4 red[16][16];
  __shared__ float cred[16];
  red[jc][e4] = acc;
  if (e4 == 0) cred[jc] = cnt;
  __syncthreads();
  for (int s = 8; s > 0; s >>= 1) {
    if (jc < s) {
      float4 o = red[jc + s][e4];
      float4 m = red[jc][e4];
      m.x += o.x; m.y += o.y; m.z += o.z; m.w += o.w;
      red[jc][e4] = m;
    }
    __syncthreads();
  }
  if (t < 16) {
    ((float4*)esum)[((size_t)g * R_ + r) * 16 + t] = red[0][t];
  }
  if (t == 0) {
    float c = 0.f;
    #pragma unroll
    for (int q = 0; q < 16; ++q) c += cred[q];
    num[g * R_ + r] = c + 1e-10f;
  }
}

// ---------------------------------------------------------------------------
// hid1 = hid2 = inputs. Grid 1024 x 256 threads, one float4 each.
// ---------------------------------------------------------------------------
__global__ __launch_bounds__(256) void k_init_hid(
    const float* __restrict__ inp, float* __restrict__ hid)
{
  size_t idx = (size_t)blockIdx.x * 256 + threadIdx.x;   // 0..262143
  float4 v = ((const float4*)inp)[idx];
  ((float4*)hid)[idx] = v;
  ((float4*)hid)[idx + (size_t)R_ * (D_ / 4)] = v;
}

// ---------------------------------------------------------------------------
// hagg[g,b] = adj_g[b] (LxL) @ hid[g,b] (LxD).  Tile 64x128, 256 thr, 4x8.
// Grid 256: bid>>4 = batch (g*8+b), (bid>>2)&3 = tm, bid&3 = tn.
// ---------------------------------------------------------------------------
__global__ __launch_bounds__(256) void k_hagg(
    const float* __restrict__ adj1, const float* __restrict__ adj2,
    const float* __restrict__ hid, float* __restrict__ out)
{
  int bid = blockIdx.x;
  int batch = bid >> 4;
  int tm = (bid >> 2) & 3;
  int tn = bid & 3;
  int g = batch >> 3, b = batch & 7;
  const float* A  = (g ? adj2 : adj1) + (size_t)b * L_ * L_;
  const float* Bm = hid + ((size_t)g * R_ + (size_t)b * L_) * D_;
  float*       C  = out + ((size_t)g * R_ + (size_t)b * L_) * D_;

  __shared__ float As[16][68];
  __shared__ float Bs[16][132];

  int t = threadIdx.x;
  int tx = t & 15, ty = t >> 4;
  float acc[4][8];
  #pragma unroll
  for (int r = 0; r < 4; ++r)
    #pragma unroll
    for (int c = 0; c < 8; ++c) acc[r][c] = 0.f;

  int am = t >> 2, ak4 = (t & 3) * 4;
  int bn4 = (t & 31) * 4, bk = t >> 5;

  for (int kt = 0; kt < 16; ++kt) {
    float4 av = *(const float4*)(A + (size_t)(tm * 64 + am) * L_ + kt * 16 + ak4);
    As[ak4 + 0][am] = av.x; As[ak4 + 1][am] = av.y;
    As[ak4 + 2][am] = av.z; As[ak4 + 3][am] = av.w;
    #pragma unroll
    for (int h = 0; h < 2; ++h) {
      int kk = bk + h * 8;
      float4 bv = *(const float4*)(Bm + (size_t)(kt * 16 + kk) * D_ + tn * 128 + bn4);
      *(float4*)&Bs[kk][bn4] = bv;
    }
    __syncthreads();
    #pragma unroll
    for (int kk = 0; kk < 16; ++kk) {
      float4 a  = *(const float4*)&As[kk][ty * 4];
      float4 p  = *(const float4*)&Bs[kk][tx * 4];
      float4 q  = *(const float4*)&Bs[kk][64 + tx * 4];
      float aa[4] = {a.x, a.y, a.z, a.w};
      float bb[8] = {p.x, p.y, p.z, p.w, q.x, q.y, q.z, q.w};
      #pragma unroll
      for (int r = 0; r < 4; ++r)
        #pragma unroll
        for (int c = 0; c < 8; ++c) acc[r][c] = fmaf(aa[r], bb[c], acc[r][c]);
    }
    __syncthreads();
  }
  #pragma unroll
  for (int r = 0; r < 4; ++r) {
    float4 o0 = {acc[r][0], acc[r][1], acc[r][2], acc[r][3]};
    float4 o1 = {acc[r][4], acc[r][5], acc[r][6], acc[r][7]};
    float* crow = C + (size_t)(tm * 64 + ty * 4 + r) * D_ + tn * 128;
    *(float4*)(crow + tx * 4) = o0;
    *(float4*)(crow + 64 + tx * 4) = o1;
  }
}

// ---------------------------------------------------------------------------
// h_e = tanh( (1/num) * ( [hagg | esum] @ W.T ) ), W = W1 (g=0) / W3 (g=1).
// M=4096, N=64, K=576.  Tile 32x64, 256 thr, 2x4.  Grid 128.
// ---------------------------------------------------------------------------
__global__ __launch_bounds__(256) void k_he(
    const float* __restrict__ hagg, const float* __restrict__ esum,
    const float* __restrict__ num,
    const float* __restrict__ W1, const float* __restrict__ W3,
    float* __restrict__ he)
{
  int r0 = blockIdx.x * 32;
  int g = r0 >> 11;
  const float* W = g ? W3 : W1;

  __shared__ float As[16][36];
  __shared__ float Bs[16][68];

  int t = threadIdx.x;
  int tx = t & 15, ty = t >> 4;
  float acc[2][4];
  #pragma unroll
  for (int r = 0; r < 2; ++r)
    #pragma unroll
    for (int c = 0; c < 4; ++c) acc[r][c] = 0.f;

  int am = t >> 3, ak2 = (t & 7) * 2;
  int bn = t >> 2, bk4 = (t & 3) * 4;

  for (int kt = 0; kt < 36; ++kt) {
    int row = r0 + am;
    float2 av;
    if (kt < 32) av = *(const float2*)(hagg + (size_t)row * D_ + kt * 16 + ak2);
    else         av = *(const float2*)(esum + (size_t)row * E_ + (kt - 32) * 16 + ak2);
    As[ak2][am] = av.x; As[ak2 + 1][am] = av.y;
    float4 bv = *(const float4*)(W + (size_t)bn * DE_ + kt * 16 + bk4);
    Bs[bk4 + 0][bn] = bv.x; Bs[bk4 + 1][bn] = bv.y;
    Bs[bk4 + 2][bn] = bv.z; Bs[bk4 + 3][bn] = bv.w;
    __syncthreads();
    #pragma unroll
    for (int kk = 0; kk < 16; ++kk) {
      float2 a = *(const float2*)&As[kk][ty * 2];
      float4 bq = *(const float4*)&Bs[kk][tx * 4];
      float aa[2] = {a.x, a.y};
      float bb[4] = {bq.x, bq.y, bq.z, bq.w};
      #pragma unroll
      for (int r = 0; r < 2; ++r)
        #pragma unroll
        for (int c = 0; c < 4; ++c) acc[r][c] = fmaf(aa[r], bb[c], acc[r][c]);
    }
    __syncthreads();
  }
  #pragma unroll
  for (int r = 0; r < 2; ++r) {
    int row = r0 + ty * 2 + r;
    float s = 1.0f / num[row];
    float4 o = {tanhf(acc[r][0] * s), tanhf(acc[r][1] * s),
                tanhf(acc[r][2] * s), tanhf(acc[r][3] * s)};
    *(float4*)(he + (size_t)row * E_ + tx * 4) = o;
  }
}

// ---------------------------------------------------------------------------
// hid_new = tanh( [h_e | hid_old] @ W.T + bias ), W = W2/W4, bias = b2/b4.
// M=4096, N=512, K=576.  Tile 64x128, 256 thr, 4x8.  Grid 256.
// Writes into `out` (the pong buffer, overwriting hagg — safe: hagg consumed).
// ---------------------------------------------------------------------------
__global__ __launch_bounds__(256) void k_hid(
    const float* __restrict__ he, const float* __restrict__ hidin,
    const float* __restrict__ W2, const float* __restrict__ W4,
    const float* __restrict__ b2, const float* __restrict__ b4,
    float* __restrict__ out)
{
  int bm = blockIdx.x >> 2;   // 0..63
  int tn = blockIdx.x & 3;
  int r0 = bm * 64;
  int g = r0 >> 11;
  const float* W    = g ? W4 : W2;
  const float* bias = g ? b4 : b2;

  __shared__ float As[16][68];
  __shared__ float Bs[16][132];

  int t = threadIdx.x;
  int tx = t & 15, ty = t >> 4;
  float acc[4][8];
  #pragma unroll
  for (int r = 0; r < 4; ++r)
    #pragma unroll
    for (int c = 0; c < 8; ++c) acc[r][c] = 0.f;

  int am = t >> 2, ak4 = (t & 3) * 4;
  int bn = t >> 2, bk4 = (t & 3) * 4;

  for (int kt = 0; kt < 36; ++kt) {
    int row = r0 + am;
    float4 av;
    if (kt < 4) av = *(const float4*)(he + (size_t)row * E_ + kt * 16 + ak4);
    else        av = *(const float4*)(hidin + (size_t)row * D_ + kt * 16 - 64 + ak4);
    As[ak4 + 0][am] = av.x; As[ak4 + 1][am] = av.y;
    As[ak4 + 2][am] = av.z; As[ak4 + 3][am] = av.w;
    #pragma unroll
    for (int h = 0; h < 2; ++h) {
      int n = bn + h * 64;
      float4 bv = *(const float4*)(W + (size_t)(tn * 128 + n) * DE_ + kt * 16 + bk4);
      Bs[bk4 + 0][n] = bv.x; Bs[bk4 + 1][n] = bv.y;
      Bs[bk4 + 2][n] = bv.z; Bs[bk4 + 3][n] = bv.w;
    }
    __syncthreads();
    #pragma unroll
    for (int kk = 0; kk < 16; ++kk) {
      float4 a  = *(const float4*)&As[kk][ty * 4];
      float4 p  = *(const float4*)&Bs[kk][tx * 4];
      float4 q  = *(const float4*)&Bs[kk][64 + tx * 4];
      float aa[4] = {a.x, a.y, a.z, a.w};
      float bb[8] = {p.x, p.y, p.z, p.w, q.x, q.y, q.z, q.w};
      #pragma unroll
      for (int r = 0; r < 4; ++r)
        #pragma unroll
        for (int c = 0; c < 8; ++c) acc[r][c] = fmaf(aa[r], bb[c], acc[r][c]);
    }
    __syncthreads();
  }
  #pragma unroll
  for (int r = 0; r < 4; ++r) {
    int row = r0 + ty * 4 + r;
    int c0 = tn * 128 + tx * 4;
    float4 o0 = {tanhf(acc[r][0] + bias[c0 + 0]), tanhf(acc[r][1] + bias[c0 + 1]),
                 tanhf(acc[r][2] + bias[c0 + 2]), tanhf(acc[r][3] + bias[c0 + 3])};
    float4 o1 = {tanhf(acc[r][4] + bias[c0 + 64]), tanhf(acc[r][5] + bias[c0 + 65]),
                 tanhf(acc[r][6] + bias[c0 + 66]), tanhf(acc[r][7] + bias[c0 + 67])};
    float* crow = out + (size_t)row * D_ + c0;
    *(float4*)(crow) = o0;
    *(float4*)(crow + 64) = o1;
  }
}

// ---------------------------------------------------------------------------
// fused = tanh( [hid1 | hid2] @ W5.T + b5 ).  M=2048, N=512, K=1024.
// Tile 64x128, grid 128.  hid = [2][2048][512] final buffer.
// ---------------------------------------------------------------------------
__global__ __launch_bounds__(256) void k_final(
    const float* __restrict__ hid, const float* __restrict__ W5,
    const float* __restrict__ b5, float* __restrict__ out)
{
  int bm = blockIdx.x >> 2;   // 0..31
  int tn = blockIdx.x & 3;
  int r0 = bm * 64;

  __shared__ float As[16][68];
  __shared__ float Bs[16][132];

  int t = threadIdx.x;
  int tx = t & 15, ty = t >> 4;
  float acc[4][8];
  #pragma unroll
  for (int r = 0; r < 4; ++r)
    #pragma unroll
    for (int c = 0; c < 8; ++c) acc[r][c] = 0.f;

  int am = t >> 2, ak4 = (t & 3) * 4;
  int bn = t >> 2, bk4 = (t & 3) * 4;

  for (int kt = 0; kt < 64; ++kt) {
    int row = r0 + am;
    const float* src = (kt < 32)
        ? (hid + (size_t)row * D_ + kt * 16)
        : (hid + (size_t)R_ * D_ + (size_t)row * D_ + (kt - 32) * 16);
    float4 av = *(const float4*)(src + ak4);
    As[ak4 + 0][am] = av.x; As[ak4 + 1][am] = av.y;
    As[ak4 + 2][am] = av.z; As[ak4 + 3][am] = av.w;
    #pragma unroll
    for (int h = 0; h < 2; ++h) {
      int n = bn + h * 64;
      float4 bv = *(const float4*)(W5 + (size_t)(tn * 128 + n) * 1024 + kt * 16 + bk4);
      Bs[bk4 + 0][n] = bv.x; Bs[bk4 + 1][n] = bv.y;
      Bs[bk4 + 2][n] = bv.z; Bs[bk4 + 3][n] = bv.w;
    }
    __syncthreads();
    #pragma unroll
    for (int kk = 0; kk < 16; ++kk) {
      float4 a  = *(const float4*)&As[kk][ty * 4];
      float4 p  = *(const float4*)&Bs[kk][tx * 4];
      float4 q  = *(const float4*)&Bs[kk][64 + tx * 4];
      float aa[4] = {a.x, a.y, a.z, a.w};
      float bb[8] = {p.x, p.y, p.z, p.w, q.x, q.y, q.z, q.w};
      #pragma unroll
      for (int r = 0; r < 4; ++r)
        #pragma unroll
        for (int c = 0; c < 8; ++c) acc[r][c] = fmaf(aa[r], bb[c], acc[r][c]);
    }
    __syncthreads();
  }
  #pragma unroll
  for (int r = 0; r < 4; ++r) {
    int row = r0 + ty * 4 + r;
    int c0 = tn * 128 + tx * 4;
    float4 o0 = {tanhf(acc[r][0] + b5[c0 + 0]), tanhf(acc[r][1] + b5[c0 + 1]),
                 tanhf(acc[r][2] + b5[c0 + 2]), tanhf(acc[r][3] + b5[c0 + 3])};
    float4 o1 = {tanhf(acc[r][4] + b5[c0 + 64]), tanhf(acc[r][5] + b5[c0 + 65]),
                 tanhf(acc[r][6] + b5[c0 + 66]), tanhf(acc[r][7] + b5[c0 + 67])};
    float* crow = out + (size_t)row * D_ + c0;
    *(float4*)(crow) = o0;
    *(float4*)(crow + 64) = o1;
  }
}

// ---------------------------------------------------------------------------
// out2[b,:] = fused[b, mains[b], :]
// ---------------------------------------------------------------------------
__global__ __launch_bounds__(512) void k_gather(
    const float* __restrict__ fused, const int* __restrict__ mains,
    float* __restrict__ out2)
{
  int b = blockIdx.x;
  int row = mains[b];
  out2[(size_t)b * D_ + threadIdx.x] =
      fused[((size_t)b * L_ + row) * D_ + threadIdx.x];
}

// ---------------------------------------------------------------------------
extern "C" void kernel_launch(void* const* d_in, const int* in_sizes, int n_in,
                              void* d_out, int out_size, void* d_ws, size_t ws_size,
                              hipStream_t stream)
{
  const float* inputs = (const float*)d_in[0];
  const int*   mains  = (const int*)d_in[1];
  const float* adj1   = (const float*)d_in[2];
  const float* adj2   = (const float*)d_in[3];
  const int*   edge1  = (const int*)d_in[4];
  const int*   edge2  = (const int*)d_in[5];
  const float* emb    = (const float*)d_in[6];
  const float* W1     = (const float*)d_in[7];
  const float* W2     = (const float*)d_in[8];
  const float* b2     = (const float*)d_in[9];
  const float* W3     = (const float*)d_in[10];
  const float* W4     = (const float*)d_in[11];
  const float* b4     = (const float*)d_in[12];
  const float* W5     = (const float*)d_in[13];
  const float* b5     = (const float*)d_in[14];
  float* out = (float*)d_out;

  float* ws   = (float*)d_ws;
  float* esum = ws;                      // [2][2048][64]  = 262144
  float* num  = esum + 262144;           // [2][2048]      = 4096
  float* hidA = num + 4096;              // [2][2048][512] = 2097152
  float* hidB = hidA + 2097152;          // [2][2048][512] = 2097152
  float* he   = hidB + 2097152;          // [2][2048][64]  = 262144
  // total 4,722,688 floats = 18.9 MB

  k_precompute<<<4096, 256, 0, stream>>>(adj1, adj2, edge1, edge2, emb, esum, num);
  k_init_hid<<<1024, 256, 0, stream>>>(inputs, hidA);

  float* ping = hidA;
  float* pong = hidB;
  for (int it = 0; it < 3; ++it) {
    k_hagg<<<256, 256, 0, stream>>>(adj1, adj2, ping, pong);
    k_he<<<128, 256, 0, stream>>>(pong, esum, num, W1, W3, he);
    k_hid<<<256, 256, 0, stream>>>(he, ping, W2, W4, b2, b4, pong);
    float* tmp = ping; ping = pong; pong = tmp;
  }
  // after 3 swaps, final hid is in `ping` (= hidB)
  k_final<<<128, 256, 0, stream>>>(ping, W5, b5, out);
  k_gather<<<8, 512, 0, stream>>>(out, mains, out + (size_t)R_ * D_);
}

// Round 6
// 363.477 us; speedup vs baseline: 1.4168x; 1.4168x over previous
//
#include <hip/hip_runtime.h>
#include <math.h>

#define B_  8
#define L_  256
#define D_  512
#define E_  64
#define DE_ 576
#define R_  2048   // B*L rows per graph
#define RG_ 4096   // rows, both graphs stacked

typedef unsigned short ushortT;
typedef __attribute__((ext_vector_type(8))) short bfrag;   // 8 bf16 (4 VGPR) MFMA operand
typedef __attribute__((ext_vector_type(4))) float f32x4;   // MFMA accumulator

#define MFMA16(a,b,c) __builtin_amdgcn_mfma_f32_16x16x32_bf16(a,b,c,0,0,0)

__device__ inline ushortT f2bf(float x){           // fp32 -> bf16 RNE
  unsigned u = __float_as_uint(x);
  u += 0x7FFFu + ((u >> 16) & 1u);
  return (ushortT)(u >> 16);
}
__device__ inline float bf2f(ushortT h){ return __uint_as_float(((unsigned)h) << 16); }

// ---------------------------------------------------------------------------
// Convert weights (hi/lo split planes) and adj (exact bf16, values {0,1}).
// blockIdx.y selects the segment. Each thread handles 4 elements.
// ---------------------------------------------------------------------------
__global__ __launch_bounds__(256) void k_cvt(
    const float* __restrict__ W1, const float* __restrict__ W3,
    const float* __restrict__ W2, const float* __restrict__ W4,
    const float* __restrict__ W5,
    const float* __restrict__ adj1, const float* __restrict__ adj2,
    ushortT* W1h, ushortT* W1l, ushortT* W3h, ushortT* W3l,
    ushortT* W2h, ushortT* W2l, ushortT* W4h, ushortT* W4l,
    ushortT* W5h, ushortT* W5l, ushortT* adjb)
{
  const float* src; ushortT *dh, *dl; int n;
  switch (blockIdx.y) {
    case 0: src = W1;  dh = W1h; dl = W1l; n = 36864;  break;
    case 1: src = W3;  dh = W3h; dl = W3l; n = 36864;  break;
    case 2: src = W2;  dh = W2h; dl = W2l; n = 294912; break;
    case 3: src = W4;  dh = W4h; dl = W4l; n = 294912; break;
    case 4: src = W5;  dh = W5h; dl = W5l; n = 524288; break;
    case 5: src = adj1; dh = adjb;          dl = 0; n = 524288; break;
    default: src = adj2; dh = adjb + 524288; dl = 0; n = 524288; break;
  }
  int i4 = blockIdx.x * 256 + threadIdx.x;
  if (i4 * 4 >= n) return;
  float4 v = ((const float4*)src)[i4];
  float xs[4] = {v.x, v.y, v.z, v.w};
  ushortT h[4], lo[4];
  #pragma unroll
  for (int i = 0; i < 4; ++i) {
    h[i] = f2bf(xs[i]);
    lo[i] = f2bf(xs[i] - bf2f(h[i]));
  }
  ((ushort4*)dh)[i4] = make_ushort4(h[0], h[1], h[2], h[3]);
  if (dl) ((ushort4*)dl)[i4] = make_ushort4(lo[0], lo[1], lo[2], lo[3]);
}

// ---------------------------------------------------------------------------
// Precompute: num = count(adj>0)+eps ; esum planes (bf16 hi/lo) =
// sum_j adj[b,i,j] * emb[edge[b,i,j],:].  Grid 4096 x 256.
// ---------------------------------------------------------------------------
__global__ __launch_bounds__(256) void k_precompute(
    const float* __restrict__ adj1, const float* __restrict__ adj2,
    const int* __restrict__ edge1, const int* __restrict__ edge2,
    const float* __restrict__ emb,
    ushortT* __restrict__ esumh, ushortT* __restrict__ esuml,
    float* __restrict__ num)
{
  int g = blockIdx.x >> 11;
  int r = blockIdx.x & 2047;
  const float* adj  = (g ? adj2 : adj1) + (size_t)r * L_;
  const int*   edge = (g ? edge2 : edge1) + (size_t)r * L_;
  const float4* emb4 = (const float4*)emb;

  int t = threadIdx.x;
  int e4 = t & 15, jc = t >> 4;
  float4 acc = {0.f, 0.f, 0.f, 0.f};
  float cnt = 0.f;
  #pragma unroll
  for (int k = 0; k < 16; ++k) {
    int j = jc * 16 + k;
    float a = adj[j];
    if (a != 0.0f) {
      int id = edge[j];
      float4 e = emb4[(size_t)id * 16 + e4];
      acc.x += a * e.x; acc.y += a * e.y; acc.z += a * e.z; acc.w += a * e.w;
      if (e4 == 0 && a > 0.0f) cnt += 1.0f;
    }
  }

  __shared__ float4 red[16][16];
  __shared__ float cred[16];
  red[jc][e4] = acc;
  if (e4 == 0) cred[jc] = cnt;
  __syncthreads();
  for (int s = 8; s > 0; s >>= 1) {
    if (jc < s) {
      float4 o = red[jc + s][e4];
      float4 m = red[jc][e4];
      m.x += o.x; m.y += o.y; m.z += o.z; m.w += o.w;
      red[jc][e4] = m;
    }
    __syncthreads();
  }
  if (t < 16) {
    float4 v = red[0][t];
    float xs[4] = {v.x, v.y, v.z, v.w};
    size_t base = ((size_t)g * R_ + r) * 64 + t * 4;
    #pragma unroll
    for (int i = 0; i < 4; ++i) {
      ushortT hi = f2bf(xs[i]);
      esumh[base + i] = hi;
      esuml[base + i] = f2bf(xs[i] - bf2f(hi));
    }
  }
  if (t == 0) {
    float c = 0.f;
    #pragma unroll
    for (int q = 0; q < 16; ++q) c += cred[q];
    num[g * R_ + r] = c + 1e-10f;
  }
}

// ---------------------------------------------------------------------------
// hid1 = hid2 = inputs, stored as bf16 hi/lo planes [4096][512].
// ---------------------------------------------------------------------------
__global__ __launch_bounds__(256) void k_init_hid(
    const float* __restrict__ inp, ushortT* __restrict__ hh, ushortT* __restrict__ hl)
{
  int idx = blockIdx.x * 256 + threadIdx.x;   // 0..262143 (float4s of one graph copy)
  float4 v = ((const float4*)inp)[idx];
  float xs[4] = {v.x, v.y, v.z, v.w};
  ushortT h[4], lo[4];
  #pragma unroll
  for (int i = 0; i < 4; ++i) {
    h[i] = f2bf(xs[i]);
    lo[i] = f2bf(xs[i] - bf2f(h[i]));
  }
  ushort4 vh = make_ushort4(h[0], h[1], h[2], h[3]);
  ushort4 vl = make_ushort4(lo[0], lo[1], lo[2], lo[3]);
  ((ushort4*)hh)[idx] = vh;              ((ushort4*)hl)[idx] = vl;              // g0
  ((ushort4*)hh)[idx + 262144] = vh;     ((ushort4*)hl)[idx + 262144] = vl;     // g1
}

// ---------------------------------------------------------------------------
// hagg = adj @ hid  (MFMA, adj exact bf16 -> 2 passes over hid hi/lo).
// Grid 512 = 16 batches x (4 m-tiles x 8 n-tiles), 256 thr = 4 waves, 64x64 tile.
// A = adj_bf16 direct-global frags; B = hid^T tile staged via LDS scatter.
// Output: hagg bf16 hi/lo planes (aliased onto the "other" hid plane set).
// ---------------------------------------------------------------------------
__global__ __launch_bounds__(256) void k_hagg(
    const ushortT* __restrict__ adjb,
    const ushortT* __restrict__ hidh, const ushortT* __restrict__ hidl,
    ushortT* __restrict__ hagh, ushortT* __restrict__ hagl)
{
  int bid = blockIdx.x;
  int batch = bid >> 5;              // g*8 + b
  int tile = bid & 31;
  int tm = tile >> 3, tn = tile & 7;
  int g = batch >> 3, b = batch & 7;
  const ushortT* A = adjb + (size_t)batch * 65536;     // [256][256] bf16
  size_t rowbase = (size_t)g * R_ + (size_t)b * L_;    // hid global row base
  int c0 = tn * 64;

  __shared__ ushortT Blds[2][64][40];   // [plane][d][j] pitch 40 (16B-aligned rows)

  int t = threadIdx.x;
  int l = t & 63, w = t >> 6;
  int wm = (w >> 1) * 32, wn = (w & 1) * 32;
  int lg = l >> 4, l16 = l & 15;

  f32x4 z = {0.f, 0.f, 0.f, 0.f};
  f32x4 acc[2][2] = {{z, z}, {z, z}};

  int sj = t >> 3;            // 0..31 : local k (= neighbor j)
  int sq = t & 7;             // d-chunk group
  int sd0 = sq * 8;

  for (int kt = 0; kt < 8; ++kt) {
    // ---- stage B tile (transpose hid[j][d] -> Blds[d][j]) ----
    size_t jglob = rowbase + kt * 32 + sj;
    bfrag vh = *(const bfrag*)(hidh + jglob * 512 + c0 + sd0);
    bfrag vl = *(const bfrag*)(hidl + jglob * 512 + c0 + sd0);
    #pragma unroll
    for (int i = 0; i < 8; ++i) {
      int ii = (i + sq) & 7;                       // rotated order: conflict-free
      Blds[0][sd0 + ii][sj] = (ushortT)vh[ii];
      Blds[1][sd0 + ii][sj] = (ushortT)vl[ii];
    }
    __syncthreads();
    // ---- A frags (direct global, adj bf16) ----
    bfrag a0 = *(const bfrag*)(A + (size_t)(tm * 64 + wm + l16) * 256 + kt * 32 + 8 * lg);
    bfrag a1 = *(const bfrag*)(A + (size_t)(tm * 64 + wm + 16 + l16) * 256 + kt * 32 + 8 * lg);
    #pragma unroll
    for (int f = 0; f < 2; ++f) {
      bfrag bh = *(const bfrag*)&Blds[0][wn + 16 * f + l16][8 * lg];
      bfrag bl = *(const bfrag*)&Blds[1][wn + 16 * f + l16][8 * lg];
      acc[0][f] = MFMA16(a0, bh, acc[0][f]);
      acc[0][f] = MFMA16(a0, bl, acc[0][f]);
      acc[1][f] = MFMA16(a1, bh, acc[1][f]);
      acc[1][f] = MFMA16(a1, bl, acc[1][f]);
    }
    __syncthreads();
  }
  // ---- epilogue: split + store hagg planes ----
  size_t orow0 = rowbase + tm * 64 + wm;
  #pragma unroll
  for (int e = 0; e < 2; ++e)
    #pragma unroll
    for (int f = 0; f < 2; ++f)
      #pragma unroll
      for (int j = 0; j < 4; ++j) {
        size_t row = orow0 + 16 * e + 4 * lg + j;
        int col = c0 + wn + 16 * f + l16;
        float x = acc[e][f][j];
        ushortT hi = f2bf(x);
        hagh[row * 512 + col] = hi;
        hagl[row * 512 + col] = f2bf(x - bf2f(hi));
      }
}

// ---------------------------------------------------------------------------
// h_e = tanh((1/num) * ([hagg|esum] @ W.T)).  1-wave blocks, 16x64 tile.
// Grid 256 x 64 thr.  All operands direct-global bf16 plane frags.
// ---------------------------------------------------------------------------
__global__ __launch_bounds__(64) void k_he(
    const ushortT* __restrict__ hagh, const ushortT* __restrict__ hagl,
    const ushortT* __restrict__ esumh, const ushortT* __restrict__ esuml,
    const float* __restrict__ num,
    const ushortT* __restrict__ W1h, const ushortT* __restrict__ W1l,
    const ushortT* __restrict__ W3h, const ushortT* __restrict__ W3l,
    ushortT* __restrict__ heh, ushortT* __restrict__ hel)
{
  int r0 = blockIdx.x * 16;
  int g = blockIdx.x >> 7;
  const ushortT* Wh = g ? W3h : W1h;
  const ushortT* Wl = g ? W3l : W1l;
  int l = threadIdx.x;
  int lg = l >> 4, l16 = l & 15;
  f32x4 z = {0.f, 0.f, 0.f, 0.f};
  f32x4 acc[4] = {z, z, z, z};
  size_t rA = r0 + l16;

  for (int kt = 0; kt < 18; ++kt) {
    const ushortT *sh, *sl; int stride, koff;
    if (kt < 16) { sh = hagh; sl = hagl; stride = 512; koff = kt * 32; }
    else         { sh = esumh; sl = esuml; stride = 64; koff = kt * 32 - 512; }
    int kk = koff + 8 * lg;
    bfrag ah = *(const bfrag*)(sh + rA * stride + kk);
    bfrag al = *(const bfrag*)(sl + rA * stride + kk);
    int kw = kt * 32 + 8 * lg;
    #pragma unroll
    for (int f = 0; f < 4; ++f) {
      bfrag bh = *(const bfrag*)(Wh + (size_t)(16 * f + l16) * DE_ + kw);
      bfrag bl = *(const bfrag*)(Wl + (size_t)(16 * f + l16) * DE_ + kw);
      acc[f] = MFMA16(ah, bh, acc[f]);
      acc[f] = MFMA16(ah, bl, acc[f]);
      acc[f] = MFMA16(al, bh, acc[f]);
    }
  }
  #pragma unroll
  for (int j = 0; j < 4; ++j) {
    size_t row = r0 + 4 * lg + j;
    float s = 1.0f / num[row];
    #pragma unroll
    for (int f = 0; f < 4; ++f) {
      float y = tanhf(acc[f][j] * s);
      int col = 16 * f + l16;
      ushortT hi = f2bf(y);
      heh[row * 64 + col] = hi;
      hel[row * 64 + col] = f2bf(y - bf2f(hi));
    }
  }
}

// ---------------------------------------------------------------------------
// hid_new = tanh([h_e | hid_old] @ W.T + bias).  Grid 512 (64 m x 8 n tiles),
// 4 waves, 64x64 tile, no LDS: direct-global frags.  3-pass split-bf16.
// ---------------------------------------------------------------------------
__global__ __launch_bounds__(256) void k_hid(
    const ushortT* __restrict__ heh, const ushortT* __restrict__ hel,
    const ushortT* __restrict__ hidh, const ushortT* __restrict__ hidl,
    const ushortT* __restrict__ W2h, const ushortT* __restrict__ W2l,
    const ushortT* __restrict__ W4h, const ushortT* __restrict__ W4l,
    const float* __restrict__ b2, const float* __restrict__ b4,
    ushortT* __restrict__ outh, ushortT* __restrict__ outl)
{
  int bm = blockIdx.x >> 3, bn = blockIdx.x & 7;
  int r0 = bm * 64, c0 = bn * 64;
  int g = bm >> 5;
  const ushortT* Wh = g ? W4h : W2h;
  const ushortT* Wl = g ? W4l : W2l;
  const float* bias = g ? b4 : b2;
  int t = threadIdx.x, l = t & 63, w = t >> 6;
  int wm = (w >> 1) * 32, wn = (w & 1) * 32;
  int lg = l >> 4, l16 = l & 15;
  f32x4 z = {0.f, 0.f, 0.f, 0.f};
  f32x4 acc[2][2] = {{z, z}, {z, z}};
  size_t rA0 = r0 + wm + l16;
  size_t nW0 = c0 + wn + l16;

  for (int kt = 0; kt < 18; ++kt) {
    const ushortT *sh, *sl; int stride, koff;
    if (kt < 2) { sh = heh; sl = hel; stride = 64; koff = kt * 32; }
    else        { sh = hidh; sl = hidl; stride = 512; koff = kt * 32 - 64; }
    int kk = koff + 8 * lg;
    bfrag a0h = *(const bfrag*)(sh + rA0 * stride + kk);
    bfrag a0l = *(const bfrag*)(sl + rA0 * stride + kk);
    bfrag a1h = *(const bfrag*)(sh + (rA0 + 16) * stride + kk);
    bfrag a1l = *(const bfrag*)(sl + (rA0 + 16) * stride + kk);
    int kw = kt * 32 + 8 * lg;
    bfrag b0h = *(const bfrag*)(Wh + nW0 * DE_ + kw);
    bfrag b0l = *(const bfrag*)(Wl + nW0 * DE_ + kw);
    bfrag b1h = *(const bfrag*)(Wh + (nW0 + 16) * DE_ + kw);
    bfrag b1l = *(const bfrag*)(Wl + (nW0 + 16) * DE_ + kw);
    acc[0][0] = MFMA16(a0h, b0h, acc[0][0]);
    acc[0][0] = MFMA16(a0h, b0l, acc[0][0]);
    acc[0][0] = MFMA16(a0l, b0h, acc[0][0]);
    acc[0][1] = MFMA16(a0h, b1h, acc[0][1]);
    acc[0][1] = MFMA16(a0h, b1l, acc[0][1]);
    acc[0][1] = MFMA16(a0l, b1h, acc[0][1]);
    acc[1][0] = MFMA16(a1h, b0h, acc[1][0]);
    acc[1][0] = MFMA16(a1h, b0l, acc[1][0]);
    acc[1][0] = MFMA16(a1l, b0h, acc[1][0]);
    acc[1][1] = MFMA16(a1h, b1h, acc[1][1]);
    acc[1][1] = MFMA16(a1h, b1l, acc[1][1]);
    acc[1][1] = MFMA16(a1l, b1h, acc[1][1]);
  }
  float bb[2] = {bias[nW0], bias[nW0 + 16]};
  #pragma unroll
  for (int e = 0; e < 2; ++e)
    #pragma unroll
    for (int f = 0; f < 2; ++f)
      #pragma unroll
      for (int j = 0; j < 4; ++j) {
        size_t row = r0 + wm + 16 * e + 4 * lg + j;
        int col = c0 + wn + 16 * f + l16;
        float y = tanhf(acc[e][f][j] + bb[f]);
        ushortT hi = f2bf(y);
        outh[row * 512 + col] = hi;
        outl[row * 512 + col] = f2bf(y - bf2f(hi));
      }
}

// ---------------------------------------------------------------------------
// fused = tanh([hid1|hid2] @ W5.T + b5) -> fp32 d_out.  Grid 256 (32x8 tiles).
// ---------------------------------------------------------------------------
__global__ __launch_bounds__(256) void k_final(
    const ushortT* __restrict__ hidh, const ushortT* __restrict__ hidl,
    const ushortT* __restrict__ W5h, const ushortT* __restrict__ W5l,
    const float* __restrict__ b5, float* __restrict__ out)
{
  int bm = blockIdx.x >> 3, bn = blockIdx.x & 7;
  int r0 = bm * 64, c0 = bn * 64;
  int t = threadIdx.x, l = t & 63, w = t >> 6;
  int wm = (w >> 1) * 32, wn = (w & 1) * 32;
  int lg = l >> 4, l16 = l & 15;
  f32x4 z = {0.f, 0.f, 0.f, 0.f};
  f32x4 acc[2][2] = {{z, z}, {z, z}};
  size_t nW0 = c0 + wn + l16;

  for (int kt = 0; kt < 32; ++kt) {
    size_t rowoff = (kt < 16) ? 0 : (size_t)R_;     // hid1 rows then hid2 rows
    int koff = (kt & 15) * 32;
    size_t rA0 = rowoff + r0 + wm + l16;
    int kk = koff + 8 * lg;
    bfrag a0h = *(const bfrag*)(hidh + rA0 * 512 + kk);
    bfrag a0l = *(const bfrag*)(hidl + rA0 * 512 + kk);
    bfrag a1h = *(const bfrag*)(hidh + (rA0 + 16) * 512 + kk);
    bfrag a1l = *(const bfrag*)(hidl + (rA0 + 16) * 512 + kk);
    int kw = kt * 32 + 8 * lg;
    bfrag b0h = *(const bfrag*)(W5h + nW0 * 1024 + kw);
    bfrag b0l = *(const bfrag*)(W5l + nW0 * 1024 + kw);
    bfrag b1h = *(const bfrag*)(W5h + (nW0 + 16) * 1024 + kw);
    bfrag b1l = *(const bfrag*)(W5l + (nW0 + 16) * 1024 + kw);
    acc[0][0] = MFMA16(a0h, b0h, acc[0][0]);
    acc[0][0] = MFMA16(a0h, b0l, acc[0][0]);
    acc[0][0] = MFMA16(a0l, b0h, acc[0][0]);
    acc[0][1] = MFMA16(a0h, b1h, acc[0][1]);
    acc[0][1] = MFMA16(a0h, b1l, acc[0][1]);
    acc[0][1] = MFMA16(a0l, b1h, acc[0][1]);
    acc[1][0] = MFMA16(a1h, b0h, acc[1][0]);
    acc[1][0] = MFMA16(a1h, b0l, acc[1][0]);
    acc[1][0] = MFMA16(a1l, b0h, acc[1][0]);
    acc[1][1] = MFMA16(a1h, b1h, acc[1][1]);
    acc[1][1] = MFMA16(a1h, b1l, acc[1][1]);
    acc[1][1] = MFMA16(a1l, b1h, acc[1][1]);
  }
  float bb[2] = {b5[nW0], b5[nW0 + 16]};
  #pragma unroll
  for (int e = 0; e < 2; ++e)
    #pragma unroll
    for (int f = 0; f < 2; ++f)
      #pragma unroll
      for (int j = 0; j < 4; ++j) {
        size_t row = r0 + wm + 16 * e + 4 * lg + j;
        int col = c0 + wn + 16 * f + l16;
        out[row * 512 + col] = tanhf(acc[e][f][j] + bb[f]);
      }
}

// ---------------------------------------------------------------------------
__global__ __launch_bounds__(512) void k_gather(
    const float* __restrict__ fused, const int* __restrict__ mains,
    float* __restrict__ out2)
{
  int b = blockIdx.x;
  int row = mains[b];
  out2[(size_t)b * D_ + threadIdx.x] =
      fused[((size_t)b * L_ + row) * D_ + threadIdx.x];
}

// ---------------------------------------------------------------------------
extern "C" void kernel_launch(void* const* d_in, const int* in_sizes, int n_in,
                              void* d_out, int out_size, void* d_ws, size_t ws_size,
                              hipStream_t stream)
{
  const float* inputs = (const float*)d_in[0];
  const int*   mains  = (const int*)d_in[1];
  const float* adj1   = (const float*)d_in[2];
  const float* adj2   = (const float*)d_in[3];
  const int*   edge1  = (const int*)d_in[4];
  const int*   edge2  = (const int*)d_in[5];
  const float* emb    = (const float*)d_in[6];
  const float* W1     = (const float*)d_in[7];
  const float* W2     = (const float*)d_in[8];
  const float* b2     = (const float*)d_in[9];
  const float* W3     = (const float*)d_in[10];
  const float* W4     = (const float*)d_in[11];
  const float* b4     = (const float*)d_in[12];
  const float* W5     = (const float*)d_in[13];
  const float* b5     = (const float*)d_in[14];
  float* out = (float*)d_out;

  char* p = (char*)d_ws;
  auto carve = [&](size_t bytes) { void* q = (void*)p; p += (bytes + 15) & ~(size_t)15; return q; };
  float*   num   = (float*)carve(4096 * 4);
  ushortT* esumh = (ushortT*)carve(262144 * 2);
  ushortT* esuml = (ushortT*)carve(262144 * 2);
  ushortT* adjb  = (ushortT*)carve(1048576 * 2);
  ushortT* W1h = (ushortT*)carve(36864 * 2),  *W1l = (ushortT*)carve(36864 * 2);
  ushortT* W3h = (ushortT*)carve(36864 * 2),  *W3l = (ushortT*)carve(36864 * 2);
  ushortT* W2h = (ushortT*)carve(294912 * 2), *W2l = (ushortT*)carve(294912 * 2);
  ushortT* W4h = (ushortT*)carve(294912 * 2), *W4l = (ushortT*)carve(294912 * 2);
  ushortT* W5h = (ushortT*)carve(524288 * 2), *W5l = (ushortT*)carve(524288 * 2);
  ushortT* heh = (ushortT*)carve(262144 * 2), *hel = (ushortT*)carve(262144 * 2);
  ushortT* H0h = (ushortT*)carve(2097152 * 2), *H0l = (ushortT*)carve(2097152 * 2);
  ushortT* H1h = (ushortT*)carve(2097152 * 2), *H1l = (ushortT*)carve(2097152 * 2);

  k_cvt<<<dim3(512, 7), 256, 0, stream>>>(W1, W3, W2, W4, W5, adj1, adj2,
      W1h, W1l, W3h, W3l, W2h, W2l, W4h, W4l, W5h, W5l, adjb);
  k_precompute<<<4096, 256, 0, stream>>>(adj1, adj2, edge1, edge2, emb, esumh, esuml, num);
  k_init_hid<<<1024, 256, 0, stream>>>(inputs, H0h, H0l);

  ushortT *ch = H0h, *cl = H0l, *oh = H1h, *ol = H1l;
  for (int it = 0; it < 3; ++it) {
    // hagg -> "other" planes (aliased; consumed by k_he before k_hid overwrites)
    k_hagg<<<512, 256, 0, stream>>>(adjb, ch, cl, oh, ol);
    k_he<<<256, 64, 0, stream>>>(oh, ol, esumh, esuml, num, W1h, W1l, W3h, W3l, heh, hel);
    k_hid<<<512, 256, 0, stream>>>(heh, hel, ch, cl, W2h, W2l, W4h, W4l, b2, b4, oh, ol);
    ushortT* th = ch; ch = oh; oh = th;
    ushortT* tl = cl; cl = ol; ol = tl;
  }
  // final hid planes are in (ch, cl)
  k_final<<<256, 256, 0, stream>>>(ch, cl, W5h, W5l, b5, out);
  k_gather<<<8, 512, 0, stream>>>(out, mains, out + (size_t)R_ * D_);
}

// Round 12
// 335.544 us; speedup vs baseline: 1.5347x; 1.0832x over previous
//
#include <hip/hip_runtime.h>
#include <math.h>

#define B_  8
#define L_  256
#define D_  512
#define E_  64
#define DE_ 576
#define R_  2048   // B*L rows per graph
#define RG_ 4096   // rows, both graphs stacked

typedef unsigned short ushortT;
typedef __attribute__((ext_vector_type(8))) short bfrag;   // 8 bf16 (4 VGPR) MFMA operand
typedef __attribute__((ext_vector_type(4))) float f32x4;   // MFMA accumulator

#define MFMA16(a,b,c) __builtin_amdgcn_mfma_f32_16x16x32_bf16(a,b,c,0,0,0)

__device__ inline ushortT f2bf(float x){           // fp32 -> bf16 RNE
  unsigned u = __float_as_uint(x);
  u += 0x7FFFu + ((u >> 16) & 1u);
  return (ushortT)(u >> 16);
}
__device__ inline float bf2f(ushortT h){ return __uint_as_float(((unsigned)h) << 16); }

// ---------------------------------------------------------------------------
// Convert weights (hi/lo split planes) and adj (exact bf16, values {0,1}).
// ---------------------------------------------------------------------------
__global__ __launch_bounds__(256) void k_cvt(
    const float* __restrict__ W1, const float* __restrict__ W3,
    const float* __restrict__ W2, const float* __restrict__ W4,
    const float* __restrict__ W5,
    const float* __restrict__ adj1, const float* __restrict__ adj2,
    ushortT* W1h, ushortT* W1l, ushortT* W3h, ushortT* W3l,
    ushortT* W2h, ushortT* W2l, ushortT* W4h, ushortT* W4l,
    ushortT* W5h, ushortT* W5l, ushortT* adjb)
{
  const float* src; ushortT *dh, *dl; int n;
  switch (blockIdx.y) {
    case 0: src = W1;  dh = W1h; dl = W1l; n = 36864;  break;
    case 1: src = W3;  dh = W3h; dl = W3l; n = 36864;  break;
    case 2: src = W2;  dh = W2h; dl = W2l; n = 294912; break;
    case 3: src = W4;  dh = W4h; dl = W4l; n = 294912; break;
    case 4: src = W5;  dh = W5h; dl = W5l; n = 524288; break;
    case 5: src = adj1; dh = adjb;          dl = 0; n = 524288; break;
    default: src = adj2; dh = adjb + 524288; dl = 0; n = 524288; break;
  }
  int i4 = blockIdx.x * 256 + threadIdx.x;
  if (i4 * 4 >= n) return;
  float4 v = ((const float4*)src)[i4];
  float xs[4] = {v.x, v.y, v.z, v.w};
  ushortT h[4], lo[4];
  #pragma unroll
  for (int i = 0; i < 4; ++i) {
    h[i] = f2bf(xs[i]);
    lo[i] = f2bf(xs[i] - bf2f(h[i]));
  }
  ((ushort4*)dh)[i4] = make_ushort4(h[0], h[1], h[2], h[3]);
  if (dl) ((ushort4*)dl)[i4] = make_ushort4(lo[0], lo[1], lo[2], lo[3]);
}

// ---------------------------------------------------------------------------
// Precompute: num = count(adj>0)+eps ; esum planes (bf16 hi/lo).
// ---------------------------------------------------------------------------
__global__ __launch_bounds__(256) void k_precompute(
    const float* __restrict__ adj1, const float* __restrict__ adj2,
    const int* __restrict__ edge1, const int* __restrict__ edge2,
    const float* __restrict__ emb,
    ushortT* __restrict__ esumh, ushortT* __restrict__ esuml,
    float* __restrict__ num)
{
  int g = blockIdx.x >> 11;
  int r = blockIdx.x & 2047;
  const float* adj  = (g ? adj2 : adj1) + (size_t)r * L_;
  const int*   edge = (g ? edge2 : edge1) + (size_t)r * L_;
  const float4* emb4 = (const float4*)emb;

  int t = threadIdx.x;
  int e4 = t & 15, jc = t >> 4;
  float4 acc = {0.f, 0.f, 0.f, 0.f};
  float cnt = 0.f;
  #pragma unroll
  for (int k = 0; k < 16; ++k) {
    int j = jc * 16 + k;
    float a = adj[j];
    if (a != 0.0f) {
      int id = edge[j];
      float4 e = emb4[(size_t)id * 16 + e4];
      acc.x += a * e.x; acc.y += a * e.y; acc.z += a * e.z; acc.w += a * e.w;
      if (e4 == 0 && a > 0.0f) cnt += 1.0f;
    }
  }

  __shared__ float4 red[16][16];
  __shared__ float cred[16];
  red[jc][e4] = acc;
  if (e4 == 0) cred[jc] = cnt;
  __syncthreads();
  for (int s = 8; s > 0; s >>= 1) {
    if (jc < s) {
      float4 o = red[jc + s][e4];
      float4 m = red[jc][e4];
      m.x += o.x; m.y += o.y; m.z += o.z; m.w += o.w;
      red[jc][e4] = m;
    }
    __syncthreads();
  }
  if (t < 16) {
    float4 v = red[0][t];
    float xs[4] = {v.x, v.y, v.z, v.w};
    size_t base = ((size_t)g * R_ + r) * 64 + t * 4;
    #pragma unroll
    for (int i = 0; i < 4; ++i) {
      ushortT hi = f2bf(xs[i]);
      esumh[base + i] = hi;
      esuml[base + i] = f2bf(xs[i] - bf2f(hi));
    }
  }
  if (t == 0) {
    float c = 0.f;
    #pragma unroll
    for (int q = 0; q < 16; ++q) c += cred[q];
    num[g * R_ + r] = c + 1e-10f;
  }
}

// ---------------------------------------------------------------------------
// hid1 = hid2 = inputs, stored as bf16 hi/lo planes [4096][512].
// ---------------------------------------------------------------------------
__global__ __launch_bounds__(256) void k_init_hid(
    const float* __restrict__ inp, ushortT* __restrict__ hh, ushortT* __restrict__ hl)
{
  int idx = blockIdx.x * 256 + threadIdx.x;
  float4 v = ((const float4*)inp)[idx];
  float xs[4] = {v.x, v.y, v.z, v.w};
  ushortT h[4], lo[4];
  #pragma unroll
  for (int i = 0; i < 4; ++i) {
    h[i] = f2bf(xs[i]);
    lo[i] = f2bf(xs[i] - bf2f(h[i]));
  }
  ushort4 vh = make_ushort4(h[0], h[1], h[2], h[3]);
  ushort4 vl = make_ushort4(lo[0], lo[1], lo[2], lo[3]);
  ((ushort4*)hh)[idx] = vh;              ((ushort4*)hl)[idx] = vl;              // g0
  ((ushort4*)hh)[idx + 262144] = vh;     ((ushort4*)hl)[idx + 262144] = vl;     // g1
}

// ---------------------------------------------------------------------------
// Z = hid @ W1c.T (cols 0..511 of W1/W3).  M=4096, N=64, K=512.
// 1-wave blocks, 16x64 tile, grid 256.  Output TRANSPOSED: ZT[64][4096] planes
// (makes k_he2's B-fragments contiguous — no LDS transpose anywhere).
// ---------------------------------------------------------------------------
__global__ __launch_bounds__(64) void k_z(
    const ushortT* __restrict__ hidh, const ushortT* __restrict__ hidl,
    const ushortT* __restrict__ W1h, const ushortT* __restrict__ W1l,
    const ushortT* __restrict__ W3h, const ushortT* __restrict__ W3l,
    ushortT* __restrict__ zth, ushortT* __restrict__ ztl)
{
  int r0 = blockIdx.x * 16;
  int g = r0 >> 11;
  const ushortT* Wh = g ? W3h : W1h;
  const ushortT* Wl = g ? W3l : W1l;
  int l = threadIdx.x;
  int lg = l >> 4, l16 = l & 15;
  f32x4 z = {0.f, 0.f, 0.f, 0.f};
  f32x4 acc[4] = {z, z, z, z};
  size_t rA = r0 + l16;

  for (int kt = 0; kt < 16; ++kt) {
    int kk = kt * 32 + 8 * lg;
    bfrag ah = *(const bfrag*)(hidh + rA * 512 + kk);
    bfrag al = *(const bfrag*)(hidl + rA * 512 + kk);
    #pragma unroll
    for (int f = 0; f < 4; ++f) {
      bfrag bh = *(const bfrag*)(Wh + (size_t)(16 * f + l16) * DE_ + kk);
      bfrag bl = *(const bfrag*)(Wl + (size_t)(16 * f + l16) * DE_ + kk);
      acc[f] = MFMA16(ah, bh, acc[f]);
      acc[f] = MFMA16(ah, bl, acc[f]);
      acc[f] = MFMA16(al, bh, acc[f]);
    }
  }
  #pragma unroll
  for (int j = 0; j < 4; ++j) {
    size_t row = r0 + 4 * lg + j;
    #pragma unroll
    for (int f = 0; f < 4; ++f) {
      int col = 16 * f + l16;
      float x = acc[f][j];
      ushortT hi = f2bf(x);
      zth[(size_t)col * RG_ + row] = hi;
      ztl[(size_t)col * RG_ + row] = f2bf(x - bf2f(hi));
    }
  }
}

// ---------------------------------------------------------------------------
// h_e = tanh((adj @ Z + esum @ We.T) / num).  1-wave blocks, 16x64, grid 256.
// adj is exact bf16 (2 passes over ZT planes); esum part 3-pass split.
// ---------------------------------------------------------------------------
__global__ __launch_bounds__(64) void k_he2(
    const ushortT* __restrict__ adjb,
    const ushortT* __restrict__ zth, const ushortT* __restrict__ ztl,
    const ushortT* __restrict__ esumh, const ushortT* __restrict__ esuml,
    const float* __restrict__ num,
    const ushortT* __restrict__ W1h, const ushortT* __restrict__ W1l,
    const ushortT* __restrict__ W3h, const ushortT* __restrict__ W3l,
    ushortT* __restrict__ heh, ushortT* __restrict__ hel)
{
  int r0 = blockIdx.x * 16;
  int g = r0 >> 11;
  int bt = r0 >> 8;                 // batch index g*8+b (matches adjb layout)
  int rl = r0 & 255;                // row base within batch
  const ushortT* A = adjb + (size_t)bt * 65536;
  const ushortT* Wh = g ? W3h : W1h;
  const ushortT* Wl = g ? W3l : W1l;
  int l = threadIdx.x;
  int lg = l >> 4, l16 = l & 15;
  f32x4 z = {0.f, 0.f, 0.f, 0.f};
  f32x4 acc[4] = {z, z, z, z};

  // adj @ Z : K = 256 (neighbors within batch)
  for (int kt = 0; kt < 8; ++kt) {
    int kk = kt * 32 + 8 * lg;
    bfrag a = *(const bfrag*)(A + (size_t)(rl + l16) * 256 + kk);
    #pragma unroll
    for (int f = 0; f < 4; ++f) {
      bfrag zh_ = *(const bfrag*)(zth + (size_t)(16 * f + l16) * RG_ + bt * 256 + kk);
      bfrag zl_ = *(const bfrag*)(ztl + (size_t)(16 * f + l16) * RG_ + bt * 256 + kk);
      acc[f] = MFMA16(a, zh_, acc[f]);
      acc[f] = MFMA16(a, zl_, acc[f]);
    }
  }
  // esum @ We.T : K = 64 (W cols 512..575)
  for (int kt = 0; kt < 2; ++kt) {
    int kk = kt * 32 + 8 * lg;
    bfrag eh = *(const bfrag*)(esumh + (size_t)(r0 + l16) * 64 + kk);
    bfrag el = *(const bfrag*)(esuml + (size_t)(r0 + l16) * 64 + kk);
    #pragma unroll
    for (int f = 0; f < 4; ++f) {
      bfrag wh = *(const bfrag*)(Wh + (size_t)(16 * f + l16) * DE_ + 512 + kk);
      bfrag wl = *(const bfrag*)(Wl + (size_t)(16 * f + l16) * DE_ + 512 + kk);
      acc[f] = MFMA16(eh, wh, acc[f]);
      acc[f] = MFMA16(eh, wl, acc[f]);
      acc[f] = MFMA16(el, wh, acc[f]);
    }
  }
  #pragma unroll
  for (int j = 0; j < 4; ++j) {
    size_t row = r0 + 4 * lg + j;
    float s = 1.0f / num[row];
    #pragma unroll
    for (int f = 0; f < 4; ++f) {
      float y = tanhf(acc[f][j] * s);
      int col = 16 * f + l16;
      ushortT hi = f2bf(y);
      heh[row * 64 + col] = hi;
      hel[row * 64 + col] = f2bf(y - bf2f(hi));
    }
  }
}

// ---------------------------------------------------------------------------
// hid_new = tanh([h_e | hid_old] @ W.T + bias).  Grid 512, 4 waves, 64x64.
// ---------------------------------------------------------------------------
__global__ __launch_bounds__(256) void k_hid(
    const ushortT* __restrict__ heh, const ushortT* __restrict__ hel,
    const ushortT* __restrict__ hidh, const ushortT* __restrict__ hidl,
    const ushortT* __restrict__ W2h, const ushortT* __restrict__ W2l,
    const ushortT* __restrict__ W4h, const ushortT* __restrict__ W4l,
    const float* __restrict__ b2, const float* __restrict__ b4,
    ushortT* __restrict__ outh, ushortT* __restrict__ outl)
{
  int bm = blockIdx.x >> 3, bn = blockIdx.x & 7;
  int r0 = bm * 64, c0 = bn * 64;
  int g = bm >> 5;
  const ushortT* Wh = g ? W4h : W2h;
  const ushortT* Wl = g ? W4l : W2l;
  const float* bias = g ? b4 : b2;
  int t = threadIdx.x, l = t & 63, w = t >> 6;
  int wm = (w >> 1) * 32, wn = (w & 1) * 32;
  int lg = l >> 4, l16 = l & 15;
  f32x4 z = {0.f, 0.f, 0.f, 0.f};
  f32x4 acc[2][2] = {{z, z}, {z, z}};
  size_t rA0 = r0 + wm + l16;
  size_t nW0 = c0 + wn + l16;

  for (int kt = 0; kt < 18; ++kt) {
    const ushortT *sh, *sl; int stride, koff;
    if (kt < 2) { sh = heh; sl = hel; stride = 64; koff = kt * 32; }
    else        { sh = hidh; sl = hidl; stride = 512; koff = kt * 32 - 64; }
    int kk = koff + 8 * lg;
    bfrag a0h = *(const bfrag*)(sh + rA0 * stride + kk);
    bfrag a0l = *(const bfrag*)(sl + rA0 * stride + kk);
    bfrag a1h = *(const bfrag*)(sh + (rA0 + 16) * stride + kk);
    bfrag a1l = *(const bfrag*)(sl + (rA0 + 16) * stride + kk);
    int kw = kt * 32 + 8 * lg;
    bfrag b0h = *(const bfrag*)(Wh + nW0 * DE_ + kw);
    bfrag b0l = *(const bfrag*)(Wl + nW0 * DE_ + kw);
    bfrag b1h = *(const bfrag*)(Wh + (nW0 + 16) * DE_ + kw);
    bfrag b1l = *(const bfrag*)(Wl + (nW0 + 16) * DE_ + kw);
    acc[0][0] = MFMA16(a0h, b0h, acc[0][0]);
    acc[0][0] = MFMA16(a0h, b0l, acc[0][0]);
    acc[0][0] = MFMA16(a0l, b0h, acc[0][0]);
    acc[0][1] = MFMA16(a0h, b1h, acc[0][1]);
    acc[0][1] = MFMA16(a0h, b1l, acc[0][1]);
    acc[0][1] = MFMA16(a0l, b1h, acc[0][1]);
    acc[1][0] = MFMA16(a1h, b0h, acc[1][0]);
    acc[1][0] = MFMA16(a1h, b0l, acc[1][0]);
    acc[1][0] = MFMA16(a1l, b0h, acc[1][0]);
    acc[1][1] = MFMA16(a1h, b1h, acc[1][1]);
    acc[1][1] = MFMA16(a1h, b1l, acc[1][1]);
    acc[1][1] = MFMA16(a1l, b1h, acc[1][1]);
  }
  float bb[2] = {bias[nW0], bias[nW0 + 16]};
  #pragma unroll
  for (int e = 0; e < 2; ++e)
    #pragma unroll
    for (int f = 0; f < 2; ++f)
      #pragma unroll
      for (int j = 0; j < 4; ++j) {
        size_t row = r0 + wm + 16 * e + 4 * lg + j;
        int col = c0 + wn + 16 * f + l16;
        float y = tanhf(acc[e][f][j] + bb[f]);
        ushortT hi = f2bf(y);
        outh[row * 512 + col] = hi;
        outl[row * 512 + col] = f2bf(y - bf2f(hi));
      }
}

// ---------------------------------------------------------------------------
// fused = tanh([hid1|hid2] @ W5.T + b5) -> fp32 d_out.  Grid 256.
// ---------------------------------------------------------------------------
__global__ __launch_bounds__(256) void k_final(
    const ushortT* __restrict__ hidh, const ushortT* __restrict__ hidl,
    const ushortT* __restrict__ W5h, const ushortT* __restrict__ W5l,
    const float* __restrict__ b5, float* __restrict__ out)
{
  int bm = blockIdx.x >> 3, bn = blockIdx.x & 7;
  int r0 = bm * 64, c0 = bn * 64;
  int t = threadIdx.x, l = t & 63, w = t >> 6;
  int wm = (w >> 1) * 32, wn = (w & 1) * 32;
  int lg = l >> 4, l16 = l & 15;
  f32x4 z = {0.f, 0.f, 0.f, 0.f};
  f32x4 acc[2][2] = {{z, z}, {z, z}};
  size_t nW0 = c0 + wn + l16;

  for (int kt = 0; kt < 32; ++kt) {
    size_t rowoff = (kt < 16) ? 0 : (size_t)R_;
    int koff = (kt & 15) * 32;
    size_t rA0 = rowoff + r0 + wm + l16;
    int kk = koff + 8 * lg;
    bfrag a0h = *(const bfrag*)(hidh + rA0 * 512 + kk);
    bfrag a0l = *(const bfrag*)(hidl + rA0 * 512 + kk);
    bfrag a1h = *(const bfrag*)(hidh + (rA0 + 16) * 512 + kk);
    bfrag a1l = *(const bfrag*)(hidl + (rA0 + 16) * 512 + kk);
    int kw = kt * 32 + 8 * lg;
    bfrag b0h = *(const bfrag*)(W5h + nW0 * 1024 + kw);
    bfrag b0l = *(const bfrag*)(W5l + nW0 * 1024 + kw);
    bfrag b1h = *(const bfrag*)(W5h + (nW0 + 16) * 1024 + kw);
    bfrag b1l = *(const bfrag*)(W5l + (nW0 + 16) * 1024 + kw);
    acc[0][0] = MFMA16(a0h, b0h, acc[0][0]);
    acc[0][0] = MFMA16(a0h, b0l, acc[0][0]);
    acc[0][0] = MFMA16(a0l, b0h, acc[0][0]);
    acc[0][1] = MFMA16(a0h, b1h, acc[0][1]);
    acc[0][1] = MFMA16(a0h, b1l, acc[0][1]);
    acc[0][1] = MFMA16(a0l, b1h, acc[0][1]);
    acc[1][0] = MFMA16(a1h, b0h, acc[1][0]);
    acc[1][0] = MFMA16(a1h, b0l, acc[1][0]);
    acc[1][0] = MFMA16(a1l, b0h, acc[1][0]);
    acc[1][1] = MFMA16(a1h, b1h, acc[1][1]);
    acc[1][1] = MFMA16(a1h, b1l, acc[1][1]);
    acc[1][1] = MFMA16(a1l, b1h, acc[1][1]);
  }
  float bb[2] = {b5[nW0], b5[nW0 + 16]};
  #pragma unroll
  for (int e = 0; e < 2; ++e)
    #pragma unroll
    for (int f = 0; f < 2; ++f)
      #pragma unroll
      for (int j = 0; j < 4; ++j) {
        size_t row = r0 + wm + 16 * e + 4 * lg + j;
        int col = c0 + wn + 16 * f + l16;
        out[row * 512 + col] = tanhf(acc[e][f][j] + bb[f]);
      }
}

// ---------------------------------------------------------------------------
__global__ __launch_bounds__(512) void k_gather(
    const float* __restrict__ fused, const int* __restrict__ mains,
    float* __restrict__ out2)
{
  int b = blockIdx.x;
  int row = mains[b];
  out2[(size_t)b * D_ + threadIdx.x] =
      fused[((size_t)b * L_ + row) * D_ + threadIdx.x];
}

// ---------------------------------------------------------------------------
extern "C" void kernel_launch(void* const* d_in, const int* in_sizes, int n_in,
                              void* d_out, int out_size, void* d_ws, size_t ws_size,
                              hipStream_t stream)
{
  const float* inputs = (const float*)d_in[0];
  const int*   mains  = (const int*)d_in[1];
  const float* adj1   = (const float*)d_in[2];
  const float* adj2   = (const float*)d_in[3];
  const int*   edge1  = (const int*)d_in[4];
  const int*   edge2  = (const int*)d_in[5];
  const float* emb    = (const float*)d_in[6];
  const float* W1     = (const float*)d_in[7];
  const float* W2     = (const float*)d_in[8];
  const float* b2     = (const float*)d_in[9];
  const float* W3     = (const float*)d_in[10];
  const float* W4     = (const float*)d_in[11];
  const float* b4     = (const float*)d_in[12];
  const float* W5     = (const float*)d_in[13];
  const float* b5     = (const float*)d_in[14];
  float* out = (float*)d_out;

  char* p = (char*)d_ws;
  auto carve = [&](size_t bytes) { void* q = (void*)p; p += (bytes + 15) & ~(size_t)15; return q; };
  float*   num   = (float*)carve(4096 * 4);
  ushortT* esumh = (ushortT*)carve(262144 * 2);
  ushortT* esuml = (ushortT*)carve(262144 * 2);
  ushortT* adjb  = (ushortT*)carve(1048576 * 2);
  ushortT* W1h = (ushortT*)carve(36864 * 2),  *W1l = (ushortT*)carve(36864 * 2);
  ushortT* W3h = (ushortT*)carve(36864 * 2),  *W3l = (ushortT*)carve(36864 * 2);
  ushortT* W2h = (ushortT*)carve(294912 * 2), *W2l = (ushortT*)carve(294912 * 2);
  ushortT* W4h = (ushortT*)carve(294912 * 2), *W4l = (ushortT*)carve(294912 * 2);
  ushortT* W5h = (ushortT*)carve(524288 * 2), *W5l = (ushortT*)carve(524288 * 2);
  ushortT* heh = (ushortT*)carve(262144 * 2), *hel = (ushortT*)carve(262144 * 2);
  ushortT* zth = (ushortT*)carve(262144 * 2), *ztl = (ushortT*)carve(262144 * 2);
  ushortT* H0h = (ushortT*)carve(2097152 * 2), *H0l = (ushortT*)carve(2097152 * 2);
  ushortT* H1h = (ushortT*)carve(2097152 * 2), *H1l = (ushortT*)carve(2097152 * 2);

  k_cvt<<<dim3(512, 7), 256, 0, stream>>>(W1, W3, W2, W4, W5, adj1, adj2,
      W1h, W1l, W3h, W3l, W2h, W2l, W4h, W4l, W5h, W5l, adjb);
  k_precompute<<<4096, 256, 0, stream>>>(adj1, adj2, edge1, edge2, emb, esumh, esuml, num);
  k_init_hid<<<1024, 256, 0, stream>>>(inputs, H0h, H0l);

  ushortT *ch = H0h, *cl = H0l, *oh = H1h, *ol = H1l;
  for (int it = 0; it < 3; ++it) {
    k_z<<<256, 64, 0, stream>>>(ch, cl, W1h, W1l, W3h, W3l, zth, ztl);
    k_he2<<<256, 64, 0, stream>>>(adjb, zth, ztl, esumh, esuml, num,
                                  W1h, W1l, W3h, W3l, heh, hel);
    k_hid<<<512, 256, 0, stream>>>(heh, hel, ch, cl, W2h, W2l, W4h, W4l, b2, b4, oh, ol);
    ushortT* th = ch; ch = oh; oh = th;
    ushortT* tl = cl; cl = ol; ol = tl;
  }
  k_final<<<256, 256, 0, stream>>>(ch, cl, W5h, W5l, b5, out);
  k_gather<<<8, 512, 0, stream>>>(out, mains, out + (size_t)R_ * D_);
}